// Round 4
// baseline (1157.566 us; speedup 1.0000x reference)
//
#include <hip/hip_runtime.h>
#include <hip/hip_bf16.h>
#include <math.h>

// Problem constants (fixed by the reference)
#define TOK   131072L       // B * H * W = 8 * 128 * 128
#define LOG2E 1.4426950408889634f

typedef __hip_bfloat16  bf16;
typedef __hip_bfloat162 bf162;
typedef __attribute__((ext_vector_type(8))) short  bf16x8;   // MFMA A/B frag (4 VGPR)
typedef __attribute__((ext_vector_type(4))) short  bf16x4;   // K=16 MFMA A/B frag (2 VGPR)
typedef __attribute__((ext_vector_type(4))) float  f32x4;    // MFMA C/D frag

__device__ __forceinline__ float gelu_f(float v) {
    return 0.5f * v * (1.0f + erff(v * 0.70710678118654752f));
}
__device__ __forceinline__ short bf16bits(float v) {
    union { bf16 h; short s; } u; u.h = __float2bfloat16(v); return u.s;
}
__device__ __forceinline__ unsigned int cvtpk_bf16(float lo, float hi) {
    unsigned int r;
    asm("v_cvt_pk_bf16_f32 %0, %1, %2" : "=v"(r) : "v"(lo), "v"(hi));
    return r;
}

// ---------------- LayerNorm over rows of 180, fp32 in -> bf16 out -------------
__global__ __launch_bounds__(256) void ln_kernel(const float* __restrict__ x,
        const float* __restrict__ w, const float* __restrict__ b,
        bf16* __restrict__ out) {
    const int lane = threadIdx.x & 63;
    const long row = ((long)blockIdx.x << 2) + (threadIdx.x >> 6);
    const float* xr = x + row * 180;
    float v0 = xr[lane];
    float v1 = xr[lane + 64];
    float v2 = (lane < 52) ? xr[lane + 128] : 0.0f;
    float s  = v0 + v1 + v2;
    float sq = v0 * v0 + v1 * v1 + v2 * v2;
    #pragma unroll
    for (int off = 32; off > 0; off >>= 1) {
        s  += __shfl_xor(s, off);
        sq += __shfl_xor(sq, off);
    }
    const float mean = s * (1.0f / 180.0f);
    const float var  = sq * (1.0f / 180.0f) - mean * mean;
    const float rs   = rsqrtf(var + 1e-5f);
    bf16* orow = out + row * 180;
    orow[lane]      = __float2bfloat16((v0 - mean) * rs * w[lane]      + b[lane]);
    orow[lane + 64] = __float2bfloat16((v1 - mean) * rs * w[lane + 64] + b[lane + 64]);
    if (lane < 52)
        orow[lane + 128] = __float2bfloat16((v2 - mean) * rs * w[lane + 128] + b[lane + 128]);
}

// ---------------- W transpose: fp32 [K][N] -> bf16 [N][K] ---------------------
template<int K, int N>
__global__ __launch_bounds__(256) void wtrans_kernel(const float* __restrict__ W,
        bf16* __restrict__ WT) {
    const int idx = blockIdx.x * 256 + threadIdx.x;
    if (idx >= K * N) return;
    const int k = idx / N, n = idx - k * N;
    WT[n * K + k] = __float2bfloat16(W[idx]);
}

// ---------------- MFMA GEMM: out[M,N] = A_bf16[M,K] @ W + bias (+epi) ---------
// W passed pre-transposed bf16 [N][K]. 64x64 tile, 256 threads, K chunks <=192.
// MODE 0: qkv (scale cols<180), bf16 out | 1: fc1 (GELU), bf16 out
// MODE 2: proj (+f32 resid), f32 out     | 3: fc2 (+f32 resid), f32 out
template<int K, int NCOLS, int MODE>
__global__ __launch_bounds__(256) void gemm_mfma(
        const bf16* __restrict__ A, const bf16* __restrict__ WT,
        const float* __restrict__ bias, const float* __restrict__ resid,
        void* __restrict__ outv) {
    __shared__ short xs [64 * 200];   // X panel:  xs[r][k]
    __shared__ short wsm[64 * 200];   // W panel: wsm[n][k] = W[k][col0+n]
    const int tid  = threadIdx.x;
    const int wave = tid >> 6;
    const int lane = tid & 63;
    const int n15  = lane & 15;
    const int quad = lane >> 4;
    const long row0 = (long)blockIdx.x * 64;
    const int  col0 = blockIdx.y * 64;
    constexpr int NCH = (K + 191) / 192;

    f32x4 acc[4] = {};

    #pragma unroll
    for (int c = 0; c < NCH; ++c) {
        const int kb = c * 192;
        if (c > 0) __syncthreads();
        const int r   = tid >> 2;
        const int seg = (tid & 3) * 48;
        {   // stage X
            const bf16* arow = A + (row0 + r) * K;
            #pragma unroll
            for (int i = 0; i < 48; i += 4) {
                const int k = kb + seg + i;
                short4 v = make_short4(0, 0, 0, 0);
                if (k + 4 <= K) v = *(const short4*)(arow + k);
                *(short4*)(xs + r * 200 + seg + i) = v;
            }
        }
        {   // stage W (bf16, pre-transposed -> vector loads)
            const int col = col0 + r;
            const bf16* wrow = WT + (long)col * K;
            #pragma unroll
            for (int i = 0; i < 48; i += 4) {
                const int k = kb + seg + i;
                short4 v = make_short4(0, 0, 0, 0);
                if (col < NCOLS && k + 4 <= K) v = *(const short4*)(wrow + k);
                *(short4*)(wsm + r * 200 + seg + i) = v;
            }
        }
        __syncthreads();
        #pragma unroll
        for (int s = 0; s < 6; ++s) {
            const int k0 = s * 32;
            const bf16x8 bfrag = *(const bf16x8*)(xs + (wave * 16 + n15) * 200 + k0 + quad * 8);
            #pragma unroll
            for (int t = 0; t < 4; ++t) {
                const bf16x8 afrag = *(const bf16x8*)(wsm + (t * 16 + n15) * 200 + k0 + quad * 8);
                acc[t] = __builtin_amdgcn_mfma_f32_16x16x32_bf16(afrag, bfrag, acc[t], 0, 0, 0);
            }
        }
    }

    // epilogue: transpose through LDS for coalesced stores
    __syncthreads();
    float* Cs = (float*)xs;          // Cs[64][68]
    #pragma unroll
    for (int t = 0; t < 4; ++t)
        #pragma unroll
        for (int r = 0; r < 4; ++r)
            Cs[(wave * 16 + n15) * 68 + t * 16 + quad * 4 + r] = acc[t][r];
    __syncthreads();

    const int  rr   = tid >> 2;
    const int  c16  = (tid & 3) * 16;
    const long grow = row0 + rr;
    #pragma unroll
    for (int j4 = 0; j4 < 4; ++j4) {
        const int col4 = col0 + c16 + j4 * 4;
        if (col4 >= NCOLS) continue;
        float v[4];
        *(f32x4*)v = *(const f32x4*)(Cs + rr * 68 + c16 + j4 * 4);
        #pragma unroll
        for (int j = 0; j < 4; ++j) v[j] += bias[col4 + j];
        if (MODE == 0) {
            if (col4 < 180) {
                #pragma unroll
                for (int j = 0; j < 4; ++j) v[j] *= 0.18257418583505536f;
            }
        } else if (MODE == 1) {
            #pragma unroll
            for (int j = 0; j < 4; ++j) v[j] = gelu_f(v[j]);
        } else {
            const float4 rv = *(const float4*)(resid + grow * NCOLS + col4);
            v[0] += rv.x; v[1] += rv.y; v[2] += rv.z; v[3] += rv.w;
        }
        if (MODE == 0 || MODE == 1) {
            short4 ou;
            ou.x = bf16bits(v[0]); ou.y = bf16bits(v[1]);
            ou.z = bf16bits(v[2]); ou.w = bf16bits(v[3]);
            *(short4*)((bf16*)outv + grow * NCOLS + col4) = ou;
        } else {
            *(float4*)((float*)outv + grow * NCOLS + col4) = *(float4*)v;
        }
    }
}

// ---------------- relative-position bias table, [h][q][k] orientation ---------
__global__ __launch_bounds__(256) void biast_kernel(const float* __restrict__ rpb,
        const int* __restrict__ rpi, float* __restrict__ biasN) {
    const int idx = blockIdx.x * 256 + threadIdx.x;   // idx = q*256 + k
    const int r = rpi[idx];
    #pragma unroll
    for (int h = 0; h < 6; ++h)
        biasN[h * 65536 + idx] = rpb[r * 6 + h];
}

// ---------------- MFMA windowed attention: one block per (window, head) -------
// 4 waves x 64 queries, NO inter-wave sync after staging.  S via
// mfma_16x16x32(K_frag, Q_frag) -> D[key][query].  The D-layout of S is
// EXACTLY the B-operand layout of mfma_16x16x16 (lane holds k=quad*4+r,
// col=q15), so PV runs as O^T = V^T x P with A-frags read b64 from the
// swizzled Vt tile and B-frags cvt_pk'd straight from the accumulator:
// no P LDS round-trip, no lsum (each lane owns its query's sum).
#define SK 40    // Ks row stride (bf16)
__global__ __launch_bounds__(256) void attn_mfma(
        const bf16* __restrict__ qkv, const float* __restrict__ biasN,
        bf16* __restrict__ attn_out) {
    __shared__ short Ks[256 * SK];       // 20480 B [key][dim0..29,pad->0]
    __shared__ short Vt[32 * 256];       // 16384 B [dim][key ^ ((dim&7)<<3)]
    __shared__ int   regid[256];         //  1024 B

    const int whid = blockIdx.x;
    const int win  = whid / 6;
    const int head = whid - win * 6;
    const int bimg = win >> 6;
    const int wi   = win & 63;
    const int whr  = wi >> 3, wwc = wi & 7;
    const int tid  = threadIdx.x;

    // ---- stage K (zero-padded dims 30,31) and swizzled V^T; region ids ----
    {
        const int t = tid;                      // key 0..255
        const int i = t >> 4, jj = t & 15;
        const int p  = whr * 16 + i;
        const int qq = wwc * 16 + jj;
        const long gr = (long)bimg * 16384 + ((p + 8) & 127) * 128 + ((qq + 8) & 127);
        const int rh = (p  < 112) ? 0 : ((p  < 120) ? 1 : 2);
        const int rw = (qq < 112) ? 0 : ((qq < 120) ? 1 : 2);
        regid[t] = rh * 3 + rw;
        const short2* base2 = (const short2*)(qkv + gr * 540 + head * 30);
        short* krow = Ks + t * SK;
        #pragma unroll
        for (int pp = 0; pp < 15; ++pp) {
            *(short2*)(krow + 2 * pp) = base2[90 + pp];        // k row
            const short2 vv = base2[180 + pp];                 // v dims 2pp,2pp+1
            const int d0 = 2 * pp, d1 = 2 * pp + 1;
            Vt[d0 * 256 + (t ^ ((d0 & 7) << 3))] = vv.x;
            Vt[d1 * 256 + (t ^ ((d1 & 7) << 3))] = vv.y;
        }
        *(short2*)(krow + 30) = make_short2(0, 0);             // zero pad dims 30,31
        Vt[30 * 256 + (t ^ 48)] = 0;                           // keep pad rows finite
        Vt[31 * 256 + (t ^ 56)] = 0;
    }
    __syncthreads();   // the ONLY block-wide sync; waves free-run afterwards

    const int lane = tid & 63, wave = tid >> 6;
    const int q15 = lane & 15, quad = lane >> 4;
    const bool boundary = (whr == 7) || (wwc == 7);
    const float* mybias = biasN + head * 65536;
    const int swz = (q15 & 7) << 3;

    for (int qt = 0; qt < 4; ++qt) {
        const int qbase = wave * 64 + qt * 16;
        // ---- Q fragment (B-operand): query qbase+q15, dims quad*8..+7 ----
        const int qi = qbase + q15;
        const int pq  = whr * 16 + (qi >> 4);
        const int qqq = wwc * 16 + (qi & 15);
        const long grq = (long)bimg * 16384 + ((pq + 8) & 127) * 128 + ((qqq + 8) & 127);
        union { bf16x8 v; short2 s[4]; } qf;
        const short2* qb = (const short2*)(qkv + grq * 540 + head * 30) + quad * 4;
        #pragma unroll
        for (int j = 0; j < 4; ++j) qf.s[j] = qb[j];

        // ---- S = K·Q^T : 16 key-tiles, D[key=quad*4+r][query=q15] ----
        f32x4 acc[16];
        #pragma unroll
        for (int kt = 0; kt < 16; ++kt) acc[kt] = (f32x4){0.f, 0.f, 0.f, 0.f};
        #pragma unroll
        for (int kt = 0; kt < 16; ++kt) {
            const bf16x8 kfrag = *(const bf16x8*)(Ks + (kt * 16 + q15) * SK + quad * 8);
            acc[kt] = __builtin_amdgcn_mfma_f32_16x16x32_bf16(kfrag, qf.v, acc[kt], 0, 0, 0);
        }

        // ---- softmax over 256 keys (cross-quad shuffles, all in-register) ----
        const int rtq = ((pq  < 112) ? 0 : ((pq  < 120) ? 1 : 2)) * 3
                      + ((qqq < 112) ? 0 : ((qqq < 120) ? 1 : 2));
        float mx = -1e30f;
        #pragma unroll
        for (int kt = 0; kt < 16; ++kt) {
            const float4 b4 = *(const float4*)(mybias + qi * 256 + kt * 16 + quad * 4);
            float bb[4] = {b4.x, b4.y, b4.z, b4.w};
            if (boundary) {
                const int4 rj = *(const int4*)(regid + kt * 16 + quad * 4);
                bb[0] += (rtq == rj.x) ? 0.f : -100.f;
                bb[1] += (rtq == rj.y) ? 0.f : -100.f;
                bb[2] += (rtq == rj.z) ? 0.f : -100.f;
                bb[3] += (rtq == rj.w) ? 0.f : -100.f;
            }
            #pragma unroll
            for (int r = 0; r < 4; ++r) {
                acc[kt][r] += bb[r];
                mx = fmaxf(mx, acc[kt][r]);
            }
        }
        mx = fmaxf(mx, __shfl_xor(mx, 16));
        mx = fmaxf(mx, __shfl_xor(mx, 32));
        float l = 0.f;
        bf16x4 pb[16];   // PV B-frags: P[k=kt*16+quad*4+r][col=q15], bf16-packed
        #pragma unroll
        for (int kt = 0; kt < 16; ++kt) {
            float pv0 = __builtin_amdgcn_exp2f((acc[kt][0] - mx) * LOG2E);
            float pv1 = __builtin_amdgcn_exp2f((acc[kt][1] - mx) * LOG2E);
            float pv2 = __builtin_amdgcn_exp2f((acc[kt][2] - mx) * LOG2E);
            float pv3 = __builtin_amdgcn_exp2f((acc[kt][3] - mx) * LOG2E);
            l += pv0 + pv1 + pv2 + pv3;
            union { unsigned int w[2]; bf16x4 v; } u;
            u.w[0] = cvtpk_bf16(pv0, pv1);
            u.w[1] = cvtpk_bf16(pv2, pv3);
            pb[kt] = u.v;
        }
        l += __shfl_xor(l, 16);
        l += __shfl_xor(l, 32);
        const float inv = 1.0f / l;   // lane's own query (q15) sum

        // ---- O^T = V^T·P : K=16 MFMAs, A=Vt b64 frags, B=pb from registers ----
        f32x4 o0 = (f32x4){0.f, 0.f, 0.f, 0.f};   // dims  0..15 tile
        f32x4 o1 = (f32x4){0.f, 0.f, 0.f, 0.f};   // dims 16..31 tile
        #pragma unroll
        for (int kt = 0; kt < 16; ++kt) {
            const int off = (kt * 16 + quad * 4) ^ swz;
            const bf16x4 va = *(const bf16x4*)(Vt + q15 * 256 + off);
            const bf16x4 vb = *(const bf16x4*)(Vt + (q15 + 16) * 256 + off);
            o0 = __builtin_amdgcn_mfma_f32_16x16x16bf16_1k(va, pb[kt], o0, 0, 0, 0);
            o1 = __builtin_amdgcn_mfma_f32_16x16x16bf16_1k(vb, pb[kt], o1, 0, 0, 0);
        }

        // ---- normalize + store: lane owns query q15, dims quad*4+r (+16) ----
        bf16* ob = attn_out + grq * 180 + head * 30 + quad * 4;
        short2 sa, sb;
        sa.x = bf16bits(o0[0] * inv); sa.y = bf16bits(o0[1] * inv);
        sb.x = bf16bits(o0[2] * inv); sb.y = bf16bits(o0[3] * inv);
        *(short2*)(ob)     = sa;
        *(short2*)(ob + 2) = sb;
        sa.x = bf16bits(o1[0] * inv); sa.y = bf16bits(o1[1] * inv);
        *(short2*)(ob + 16) = sa;                       // dims 16+quad*4, +1
        if (quad < 3) {                                  // dims 30,31 are pad
            sb.x = bf16bits(o1[2] * inv); sb.y = bf16bits(o1[3] * inv);
            *(short2*)(ob + 18) = sb;
        }
    }
}

// ---------------- depthwise 5x5 conv + GELU + residual (z = y + gelu(conv)) ---
// Row-streaming with 1-step-ahead prefetch: each thread owns (image, band of 8
// rows, x-group of 4, channel pair).  Six row buffers rotate statically; at
// STEP T all 5 needed rows are already resident and the step issues the load
// for row T+3 (used next step) BEFORE its 200-FMA chain -> load->use distance
// of a full step (~640 cy) hides L2/HBM latency.  Prologue loads rows -2..+2;
// steps 0..6 prefetch rows 3..9 (exact, no wasted loads).
// Accumulation order matches the original (bias, dy 0..4, dx 0..4) exactly.
__global__ __launch_bounds__(256) void dwconv_kernel(const bf16* __restrict__ y,
        const float* __restrict__ dww, const float* __restrict__ dwb,
        bf16* __restrict__ z) {
    __shared__ float wl[25 * 360];   // [tap][ch]
    __shared__ float bl[360];
    const int tid = threadIdx.x;
    for (int e = tid; e < 9000; e += 256) {
        const int ch = e / 25;
        const int tap = e - ch * 25;
        wl[tap * 360 + ch] = dww[e];
    }
    for (int e = tid; e < 360; e += 256) bl[e] = dwb[e];
    __syncthreads();

    // gid in [0, 737280): pr = gid%180; g0 = gid/180 in [0,4096):
    //   xg = g0&31, u = g0>>5 in [0,128): im = u>>4, band = u&15 (8 rows each).
    const int gid = blockIdx.x * 256 + tid;
    const int g0  = gid / 180;
    const int pr  = gid - g0 * 180;
    const int xg  = g0 & 31;
    const int u   = g0 >> 5;
    const int im  = u >> 4;
    const int ph0 = (u & 15) << 3;         // band start row (8 rows per band)
    const int x0  = xg << 2;
    const float2 bias2 = *(const float2*)(bl + 2 * pr);

    const bf162* ybase = (const bf162*)y + ((long)im << 14) * 180 + pr;
    bf162*       zbase = (bf162*)z + (((long)im << 14) + ((long)ph0 << 7) + x0) * 180 + pr;

#define LOADROW(R, HY) { \
    const int hy_ = (HY); \
    if ((unsigned)hy_ < 128u) { \
        const bf162* row_ = ybase + ((long)hy_ << 7) * 180; \
        _Pragma("unroll") \
        for (int xx = 0; xx < 8; ++xx) { \
            const int wx_ = x0 + xx - 2; \
            R[xx] = ((unsigned)wx_ < 128u) ? __bfloat1622float2(row_[wx_ * 180]) \
                                           : make_float2(0.f, 0.f); \
        } \
    } else { \
        _Pragma("unroll") for (int xx = 0; xx < 8; ++xx) R[xx] = make_float2(0.f, 0.f); \
    } }

#define ACCJ(R, J) { \
    _Pragma("unroll") \
    for (int d = 0; d < 5; ++d) { \
        const float2 w2 = *(const float2*)(wl + ((J) * 5 + d) * 360 + 2 * pr); \
        s0.x += R[d].x     * w2.x; s0.y += R[d].y     * w2.y; \
        s1.x += R[d + 1].x * w2.x; s1.y += R[d + 1].y * w2.y; \
        s2.x += R[d + 2].x * w2.x; s2.y += R[d + 2].y * w2.y; \
        s3.x += R[d + 3].x * w2.x; s3.y += R[d + 3].y * w2.y; \
    } }

// STEP T: rows T-2..T+2 already in RA..RE; prefetch row T+3 into RP (PF=1).
#define STEP(T, RA, RB, RC, RD, RE, RP, PF) { \
    if (PF) LOADROW(RP, ph0 + (T) + 3); \
    float2 s0 = bias2, s1 = bias2, s2 = bias2, s3 = bias2; \
    ACCJ(RA, 0); ACCJ(RB, 1); ACCJ(RC, 2); ACCJ(RD, 3); ACCJ(RE, 4); \
    bf162* zr = zbase + ((long)(T) << 7) * 180; \
    bf162 ov; \
    ov.x = __float2bfloat16(RC[2].x + gelu_f(s0.x)); \
    ov.y = __float2bfloat16(RC[2].y + gelu_f(s0.y)); zr[0]   = ov; \
    ov.x = __float2bfloat16(RC[3].x + gelu_f(s1.x)); \
    ov.y = __float2bfloat16(RC[3].y + gelu_f(s1.y)); zr[180] = ov; \
    ov.x = __float2bfloat16(RC[4].x + gelu_f(s2.x)); \
    ov.y = __float2bfloat16(RC[4].y + gelu_f(s2.y)); zr[360] = ov; \
    ov.x = __float2bfloat16(RC[5].x + gelu_f(s3.x)); \
    ov.y = __float2bfloat16(RC[5].y + gelu_f(s3.y)); zr[540] = ov; \
    }

    float2 r0[8], r1[8], r2[8], r3[8], r4[8], r5[8];
    LOADROW(r0, ph0 - 2);
    LOADROW(r1, ph0 - 1);
    LOADROW(r2, ph0);
    LOADROW(r3, ph0 + 1);
    LOADROW(r4, ph0 + 2);

    STEP(0, r0, r1, r2, r3, r4, r5, 1);
    STEP(1, r1, r2, r3, r4, r5, r0, 1);
    STEP(2, r2, r3, r4, r5, r0, r1, 1);
    STEP(3, r3, r4, r5, r0, r1, r2, 1);
    STEP(4, r4, r5, r0, r1, r2, r3, 1);
    STEP(5, r5, r0, r1, r2, r3, r4, 1);
    STEP(6, r0, r1, r2, r3, r4, r5, 1);
    STEP(7, r1, r2, r3, r4, r5, r0, 0);

#undef STEP
#undef ACCJ
#undef LOADROW
}

// ---------------- launch --------------------------------------------------------
extern "C" void kernel_launch(void* const* d_in, const int* in_sizes, int n_in,
                              void* d_out, int out_size, void* d_ws, size_t ws_size,
                              hipStream_t stream) {
    const float* x    = (const float*)d_in[0];
    // d_in[1] = attn_mask: unused (mask recomputed analytically in-kernel)
    const int*   rpi  = (const int*)d_in[2];
    const float* n1w  = (const float*)d_in[3];
    const float* n1b  = (const float*)d_in[4];
    const float* wqkv = (const float*)d_in[5];
    const float* bqkv = (const float*)d_in[6];
    const float* rpb  = (const float*)d_in[7];
    const float* pw   = (const float*)d_in[8];
    const float* pb   = (const float*)d_in[9];
    const float* n2w  = (const float*)d_in[10];
    const float* n2b  = (const float*)d_in[11];
    const float* f1w  = (const float*)d_in[12];
    const float* f1b  = (const float*)d_in[13];
    const float* dww  = (const float*)d_in[14];
    const float* dwb  = (const float*)d_in[15];
    const float* f2w  = (const float*)d_in[16];
    const float* f2b  = (const float*)d_in[17];
    float* out = (float*)d_out;

    // workspace: qkvb 141.6MB | abuf 47.2MB | biasN 1.57MB | WT bufs 0.52MB
    const size_t NEED = 540L * TOK * 2 + 180L * TOK * 2 + 393216L * 4 + 259200L * 2;
    if (ws_size < NEED) return;

    bf16* qkvb = (bf16*)d_ws;
    bf16* abuf = qkvb + 540L * TOK;
    bf16* ybuf = qkvb;                    // alias: qkv dead after attention
    bf16* zbuf = qkvb + 360L * TOK;       // spans qkvb tail + abuf (both dead)
    float* biasN = (float*)(qkvb + 720L * TOK);
    bf16* wqkvT = (bf16*)(biasN + 393216);
    bf16* projT = wqkvT + 97200;
    bf16* fc1T  = projT + 32400;
    bf16* fc2T  = fc1T + 64800;

    wtrans_kernel<180, 540><<<380, 256, 0, stream>>>(wqkv, wqkvT);
    wtrans_kernel<180, 180><<<127, 256, 0, stream>>>(pw, projT);
    wtrans_kernel<180, 360><<<254, 256, 0, stream>>>(f1w, fc1T);
    wtrans_kernel<360, 180><<<254, 256, 0, stream>>>(f2w, fc2T);
    biast_kernel<<<256, 256, 0, stream>>>(rpb, rpi, biasN);

    ln_kernel<<<32768, 256, 0, stream>>>(x, n1w, n1b, abuf);
    gemm_mfma<180, 540, 0><<<dim3(2048, 9), 256, 0, stream>>>(abuf, wqkvT, bqkv, nullptr, qkvb);
    attn_mfma<<<3072, 256, 0, stream>>>(qkvb, biasN, abuf);         // abuf := attn_out
    gemm_mfma<180, 180, 2><<<dim3(2048, 3), 256, 0, stream>>>(abuf, projT, pb, x, out);  // out := x2
    ln_kernel<<<32768, 256, 0, stream>>>(out, n2w, n2b, abuf);      // abuf := xn2
    gemm_mfma<180, 360, 1><<<dim3(2048, 6), 256, 0, stream>>>(abuf, fc1T, f1b, nullptr, ybuf);
    dwconv_kernel<<<2880, 256, 0, stream>>>(ybuf, dww, dwb, zbuf);
    gemm_mfma<360, 180, 3><<<dim3(2048, 3), 256, 0, stream>>>(zbuf, fc2T, f2b, out, out);
}

// Round 6
// 805.806 us; speedup vs baseline: 1.4365x; 1.4365x over previous
//
#include <hip/hip_runtime.h>
#include <hip/hip_bf16.h>
#include <math.h>

// Problem constants (fixed by the reference)
#define TOK   131072L       // B * H * W = 8 * 128 * 128
#define LOG2E 1.4426950408889634f

typedef __hip_bfloat16  bf16;
typedef __hip_bfloat162 bf162;
typedef __attribute__((ext_vector_type(8))) short  bf16x8;   // MFMA A/B frag (4 VGPR)
typedef __attribute__((ext_vector_type(4))) float  f32x4;    // MFMA C/D frag

__device__ __forceinline__ float gelu_f(float v) {
    return 0.5f * v * (1.0f + erff(v * 0.70710678118654752f));
}
__device__ __forceinline__ short bf16bits(float v) {
    union { bf16 h; short s; } u; u.h = __float2bfloat16(v); return u.s;
}

// ---------------- LayerNorm over rows of 180, fp32 in -> bf16 out -------------
__global__ __launch_bounds__(256) void ln_kernel(const float* __restrict__ x,
        const float* __restrict__ w, const float* __restrict__ b,
        bf16* __restrict__ out) {
    const int lane = threadIdx.x & 63;
    const long row = ((long)blockIdx.x << 2) + (threadIdx.x >> 6);
    const float* xr = x + row * 180;
    float v0 = xr[lane];
    float v1 = xr[lane + 64];
    float v2 = (lane < 52) ? xr[lane + 128] : 0.0f;
    float s  = v0 + v1 + v2;
    float sq = v0 * v0 + v1 * v1 + v2 * v2;
    #pragma unroll
    for (int off = 32; off > 0; off >>= 1) {
        s  += __shfl_xor(s, off);
        sq += __shfl_xor(sq, off);
    }
    const float mean = s * (1.0f / 180.0f);
    const float var  = sq * (1.0f / 180.0f) - mean * mean;
    const float rs   = rsqrtf(var + 1e-5f);
    bf16* orow = out + row * 180;
    orow[lane]      = __float2bfloat16((v0 - mean) * rs * w[lane]      + b[lane]);
    orow[lane + 64] = __float2bfloat16((v1 - mean) * rs * w[lane + 64] + b[lane + 64]);
    if (lane < 52)
        orow[lane + 128] = __float2bfloat16((v2 - mean) * rs * w[lane + 128] + b[lane + 128]);
}

// ------- W transpose+pad: fp32 [K][N] -> bf16 [NP][KP], zero-filled pads ------
template<int K, int N, int KP, int NP>
__global__ __launch_bounds__(256) void wtrans_kernel(const float* __restrict__ W,
        bf16* __restrict__ WT) {
    const int idx = blockIdx.x * 256 + threadIdx.x;
    if (idx >= KP * NP) return;
    const int n = idx / KP, k = idx - n * KP;
    WT[idx] = (n < N && k < K) ? __float2bfloat16(W[k * N + n])
                               : __float2bfloat16(0.0f);
}

// ---------------- zero a small guard strip (keeps K-overrun reads finite) -----
__global__ void guardz_kernel(bf16* __restrict__ g) {
    if (threadIdx.x < 192) g[threadIdx.x] = __float2bfloat16(0.0f);
}

// ---------------- X-stationary MFMA GEMM ---------------------------------------
// out[M,N] = A_bf16[M,AS(logical K)] @ W + bias (+epi).  W pre-transposed,
// K-padded to KP=NCH*192 and N-padded to NPAN*64, zero-filled -> staging is
// UNCONDITIONAL (X K-pad reads neighbor-row garbage, nullified by W zeros).
// X panel (64 rows) staged ONCE; loop over NPAN 64-col W panels (per-chunk
// restage for NCH=2).  Epilogue stores directly from accumulators.
// MODE 0: qkv (scale cols<180), bf16 out | 1: fc1 (GELU), bf16 out
// MODE 2: proj (+f32 resid), f32 out     | 3: fc2 (+f32 resid), f32 out
template<int AS, int NCH, int NPAN, int NCOLS, int MODE>
__global__ __launch_bounds__(256) void gemm_xstat(
        const bf16* __restrict__ A, const bf16* __restrict__ WT,
        const float* __restrict__ bias, const float* __restrict__ resid,
        void* __restrict__ outv) {
    constexpr int XSW = NCH * 200;          // xs row stride (shorts)
    constexpr int KP  = NCH * 192;
    __shared__ short xs [64 * XSW];         // X panel: xs[r][c*200 + k]
    __shared__ short wsm[64 * 200];         // W panel (one 192-chunk)
    const int tid  = threadIdx.x;
    const int wave = tid >> 6;
    const int lane = tid & 63;
    const int n15  = lane & 15;
    const int quad = lane >> 4;
    const long row0 = (long)blockIdx.x * 64;
    const int r   = tid >> 2;
    const int seg = (tid & 3) * 48;

    // ---- stage X once: unconditional 8B loads ----
    #pragma unroll
    for (int c = 0; c < NCH; ++c) {
        const bf16* arow = A + (row0 + r) * AS + c * 192 + seg;
        #pragma unroll
        for (int i = 0; i < 48; i += 4)
            *(short4*)(xs + r * XSW + c * 200 + seg + i) = *(const short4*)(arow + i);
    }

    for (int p = 0; p < NPAN; ++p) {
        f32x4 acc[4] = {};
        #pragma unroll
        for (int c = 0; c < NCH; ++c) {
            __syncthreads();   // prior MFMA reads of wsm done (also covers xs writes)
            {   // stage W panel p, chunk c: unconditional 16B loads
                const bf16* wrow = WT + (long)(p * 64 + r) * KP + c * 192 + seg;
                #pragma unroll
                for (int i = 0; i < 48; i += 8)
                    *(bf16x8*)(wsm + r * 200 + seg + i) = *(const bf16x8*)(wrow + i);
            }
            __syncthreads();
            #pragma unroll
            for (int s = 0; s < 6; ++s) {
                const int k0 = s * 32;
                const bf16x8 bfrag = *(const bf16x8*)(xs + (wave * 16 + n15) * XSW
                                                      + c * 200 + k0 + quad * 8);
                #pragma unroll
                for (int t = 0; t < 4; ++t) {
                    const bf16x8 afrag = *(const bf16x8*)(wsm + (t * 16 + n15) * 200
                                                          + k0 + quad * 8);
                    acc[t] = __builtin_amdgcn_mfma_f32_16x16x32_bf16(afrag, bfrag, acc[t], 0, 0, 0);
                }
            }
        }
        // ---- epilogue: lane owns row (wave*16+n15), cols p*64 + t*16 + quad*4 ----
        const long grow = row0 + wave * 16 + n15;
        #pragma unroll
        for (int t = 0; t < 4; ++t) {
            const int col4 = p * 64 + t * 16 + quad * 4;
            if (col4 >= NCOLS) continue;
            float v[4];
            #pragma unroll
            for (int j = 0; j < 4; ++j) v[j] = acc[t][j] + bias[col4 + j];
            if (MODE == 0) {
                if (col4 < 180) {
                    #pragma unroll
                    for (int j = 0; j < 4; ++j) v[j] *= 0.18257418583505536f;
                }
            } else if (MODE == 1) {
                #pragma unroll
                for (int j = 0; j < 4; ++j) v[j] = gelu_f(v[j]);
            } else {
                const float4 rv = *(const float4*)(resid + grow * NCOLS + col4);
                v[0] += rv.x; v[1] += rv.y; v[2] += rv.z; v[3] += rv.w;
            }
            if (MODE == 0 || MODE == 1) {
                short4 ou;
                ou.x = bf16bits(v[0]); ou.y = bf16bits(v[1]);
                ou.z = bf16bits(v[2]); ou.w = bf16bits(v[3]);
                *(short4*)((bf16*)outv + grow * NCOLS + col4) = ou;
            } else {
                *(f32x4*)((float*)outv + grow * NCOLS + col4) = *(f32x4*)v;
            }
        }
    }
}

// ---------------- relative-position bias table, [h][q][k] orientation ---------
__global__ __launch_bounds__(256) void biast_kernel(const float* __restrict__ rpb,
        const int* __restrict__ rpi, float* __restrict__ biasN) {
    const int idx = blockIdx.x * 256 + threadIdx.x;   // idx = q*256 + k
    const int r = rpi[idx];
    #pragma unroll
    for (int h = 0; h < 6; ++h)
        biasN[h * 65536 + idx] = rpb[r * 6 + h];
}

// ---------------- MFMA windowed attention: one block per (window, head) -------
// 4 waves x 64 queries. S via mfma(K_frag, Q_frag) -> D[key][query]; softmax in
// registers (cross-quad shuffles); P -> per-wave LDS (A-layout); PV via
// mfma(P_frag, Vt_frag) -> D[query][dim]. Mask analytic; bias [h][q][k] float4.
#define SK 40    // Ks row stride (bf16): 2-way-free banks, 16B aligned
#define SP 264   // Vt / P row stride (bf16): 2-way-free banks, 16B aligned
__global__ __launch_bounds__(256) void attn_mfma(
        const bf16* __restrict__ qkv, const float* __restrict__ biasN,
        bf16* __restrict__ attn_out) {
    __shared__ short Ks[256 * SK];       // 20480 B [key][dim0..29,pad->0]
    __shared__ short Vt[32 * SP];        // 16896 B [dim][key]
    __shared__ short Pl[4][16 * SP];     // 33792 B per-wave P[q][key]
    __shared__ int   regid[256];
    __shared__ float lsum[4][16];

    const int whid = blockIdx.x;
    const int win  = whid / 6;
    const int head = whid - win * 6;
    const int bimg = win >> 6;
    const int wi   = win & 63;
    const int whr  = wi >> 3, wwc = wi & 7;
    const int tid  = threadIdx.x;

    // ---- stage K (zero-padded dims 30,31) and V^T; region ids ----
    {
        const int t = tid;                      // key 0..255
        const int i = t >> 4, jj = t & 15;
        const int p  = whr * 16 + i;
        const int qq = wwc * 16 + jj;
        const long gr = (long)bimg * 16384 + ((p + 8) & 127) * 128 + ((qq + 8) & 127);
        const int rh = (p  < 112) ? 0 : ((p  < 120) ? 1 : 2);
        const int rw = (qq < 112) ? 0 : ((qq < 120) ? 1 : 2);
        regid[t] = rh * 3 + rw;
        const short2* base2 = (const short2*)(qkv + gr * 540 + head * 30);
        short* krow = Ks + t * SK;
        #pragma unroll
        for (int pp = 0; pp < 15; ++pp) {
            *(short2*)(krow + 2 * pp) = base2[90 + pp];        // k row
            const short2 vv = base2[180 + pp];                 // v dims 2pp,2pp+1
            Vt[(2 * pp)     * SP + t] = vv.x;
            Vt[(2 * pp + 1) * SP + t] = vv.y;
        }
        *(short2*)(krow + 30) = make_short2(0, 0);             // zero pad dims 30,31
        Vt[30 * SP + t] = 0;                                   // keep pad rows finite
        Vt[31 * SP + t] = 0;
    }
    __syncthreads();

    const int wave = tid >> 6, lane = tid & 63;
    const int q15 = lane & 15, quad = lane >> 4;
    const bool boundary = (whr == 7) || (wwc == 7);
    const float* mybias = biasN + head * 65536;
    short* Pw = Pl[wave];

    for (int qt = 0; qt < 4; ++qt) {
        const int qbase = wave * 64 + qt * 16;
        // ---- Q fragment (B-operand): query qbase+q15, dims quad*8..+7 ----
        const int qi = qbase + q15;
        const int pq  = whr * 16 + (qi >> 4);
        const int qqq = wwc * 16 + (qi & 15);
        const long grq = (long)bimg * 16384 + ((pq + 8) & 127) * 128 + ((qqq + 8) & 127);
        union { bf16x8 v; short2 s[4]; } qf;
        const short2* qb = (const short2*)(qkv + grq * 540 + head * 30) + quad * 4;
        #pragma unroll
        for (int j = 0; j < 4; ++j) qf.s[j] = qb[j];

        // ---- S = K·Q^T : 16 key-tiles, D[key=quad*4+r][query=q15] ----
        f32x4 acc[16];
        #pragma unroll
        for (int kt = 0; kt < 16; ++kt) acc[kt] = (f32x4){0.f, 0.f, 0.f, 0.f};
        #pragma unroll
        for (int kt = 0; kt < 16; ++kt) {
            const bf16x8 kfrag = *(const bf16x8*)(Ks + (kt * 16 + q15) * SK + quad * 8);
            acc[kt] = __builtin_amdgcn_mfma_f32_16x16x32_bf16(kfrag, qf.v, acc[kt], 0, 0, 0);
        }

        // ---- softmax over 256 keys (64 in-register + cross-quad shuffles) ----
        const int rtq = ((pq  < 112) ? 0 : ((pq  < 120) ? 1 : 2)) * 3
                      + ((qqq < 112) ? 0 : ((qqq < 120) ? 1 : 2));
        float mx = -1e30f;
        #pragma unroll
        for (int kt = 0; kt < 16; ++kt) {
            const float4 b4 = *(const float4*)(mybias + qi * 256 + kt * 16 + quad * 4);
            float bb[4] = {b4.x, b4.y, b4.z, b4.w};
            if (boundary) {
                const int4 rj = *(const int4*)(regid + kt * 16 + quad * 4);
                bb[0] += (rtq == rj.x) ? 0.f : -100.f;
                bb[1] += (rtq == rj.y) ? 0.f : -100.f;
                bb[2] += (rtq == rj.z) ? 0.f : -100.f;
                bb[3] += (rtq == rj.w) ? 0.f : -100.f;
            }
            #pragma unroll
            for (int r = 0; r < 4; ++r) {
                acc[kt][r] += bb[r];
                mx = fmaxf(mx, acc[kt][r]);
            }
        }
        mx = fmaxf(mx, __shfl_xor(mx, 16));
        mx = fmaxf(mx, __shfl_xor(mx, 32));
        float l = 0.f;
        #pragma unroll
        for (int kt = 0; kt < 16; ++kt) {
            short4 pk;
            float pv0 = __builtin_amdgcn_exp2f((acc[kt][0] - mx) * LOG2E);
            float pv1 = __builtin_amdgcn_exp2f((acc[kt][1] - mx) * LOG2E);
            float pv2 = __builtin_amdgcn_exp2f((acc[kt][2] - mx) * LOG2E);
            float pv3 = __builtin_amdgcn_exp2f((acc[kt][3] - mx) * LOG2E);
            l += pv0 + pv1 + pv2 + pv3;
            pk.x = bf16bits(pv0); pk.y = bf16bits(pv1);
            pk.z = bf16bits(pv2); pk.w = bf16bits(pv3);
            *(short4*)(Pw + q15 * SP + kt * 16 + quad * 4) = pk;
        }
        l += __shfl_xor(l, 16);
        l += __shfl_xor(l, 32);
        if (quad == 0) lsum[wave][q15] = l;
        __syncthreads();   // uniform: all waves execute 4 qt iterations

        // ---- O = P·V : 8 key-chunks x 2 dim-tiles, D[query=quad*4+r][dim=q15] ----
        f32x4 o0 = (f32x4){0.f, 0.f, 0.f, 0.f};
        f32x4 o1 = (f32x4){0.f, 0.f, 0.f, 0.f};
        #pragma unroll
        for (int kc = 0; kc < 8; ++kc) {
            const bf16x8 pfrag = *(const bf16x8*)(Pw + q15 * SP + kc * 32 + quad * 8);
            const bf16x8 v0f = *(const bf16x8*)(Vt + q15 * SP + kc * 32 + quad * 8);
            const bf16x8 v1f = *(const bf16x8*)(Vt + (q15 + 16) * SP + kc * 32 + quad * 8);
            o0 = __builtin_amdgcn_mfma_f32_16x16x32_bf16(pfrag, v0f, o0, 0, 0, 0);
            o1 = __builtin_amdgcn_mfma_f32_16x16x32_bf16(pfrag, v1f, o1, 0, 0, 0);
        }
        // ---- normalize + scatter to token order ----
        #pragma unroll
        for (int r = 0; r < 4; ++r) {
            const int qr = qbase + quad * 4 + r;
            const float inv = 1.0f / lsum[wave][quad * 4 + r];
            const int pr  = whr * 16 + (qr >> 4);
            const int qqr = wwc * 16 + (qr & 15);
            const long gro = (long)bimg * 16384 + ((pr + 8) & 127) * 128 + ((qqr + 8) & 127);
            bf16* ob = attn_out + gro * 180 + head * 30;
            ob[q15] = __float2bfloat16(o0[r] * inv);
            if (q15 < 14) ob[q15 + 16] = __float2bfloat16(o1[r] * inv);
        }
    }
}

// ---------------- depthwise 5x5 conv + GELU + residual (z = y + gelu(conv)) ---
// Row-streaming with 1-step-ahead prefetch; six row buffers rotate statically.
__global__ __launch_bounds__(256) void dwconv_kernel(const bf16* __restrict__ y,
        const float* __restrict__ dww, const float* __restrict__ dwb,
        bf16* __restrict__ z) {
    __shared__ float wl[25 * 360];   // [tap][ch]
    __shared__ float bl[360];
    const int tid = threadIdx.x;
    for (int e = tid; e < 9000; e += 256) {
        const int ch = e / 25;
        const int tap = e - ch * 25;
        wl[tap * 360 + ch] = dww[e];
    }
    for (int e = tid; e < 360; e += 256) bl[e] = dwb[e];
    __syncthreads();

    const int gid = blockIdx.x * 256 + tid;
    const int g0  = gid / 180;
    const int pr  = gid - g0 * 180;
    const int xg  = g0 & 31;
    const int u   = g0 >> 5;
    const int im  = u >> 4;
    const int ph0 = (u & 15) << 3;         // band start row (8 rows per band)
    const int x0  = xg << 2;
    const float2 bias2 = *(const float2*)(bl + 2 * pr);

    const bf162* ybase = (const bf162*)y + ((long)im << 14) * 180 + pr;
    bf162*       zbase = (bf162*)z + (((long)im << 14) + ((long)ph0 << 7) + x0) * 180 + pr;

#define LOADROW(R, HY) { \
    const int hy_ = (HY); \
    if ((unsigned)hy_ < 128u) { \
        const bf162* row_ = ybase + ((long)hy_ << 7) * 180; \
        _Pragma("unroll") \
        for (int xx = 0; xx < 8; ++xx) { \
            const int wx_ = x0 + xx - 2; \
            R[xx] = ((unsigned)wx_ < 128u) ? __bfloat1622float2(row_[wx_ * 180]) \
                                           : make_float2(0.f, 0.f); \
        } \
    } else { \
        _Pragma("unroll") for (int xx = 0; xx < 8; ++xx) R[xx] = make_float2(0.f, 0.f); \
    } }

#define ACCJ(R, J) { \
    _Pragma("unroll") \
    for (int d = 0; d < 5; ++d) { \
        const float2 w2 = *(const float2*)(wl + ((J) * 5 + d) * 360 + 2 * pr); \
        s0.x += R[d].x     * w2.x; s0.y += R[d].y     * w2.y; \
        s1.x += R[d + 1].x * w2.x; s1.y += R[d + 1].y * w2.y; \
        s2.x += R[d + 2].x * w2.x; s2.y += R[d + 2].y * w2.y; \
        s3.x += R[d + 3].x * w2.x; s3.y += R[d + 3].y * w2.y; \
    } }

#define STEP(T, RA, RB, RC, RD, RE, RP, PF) { \
    if (PF) LOADROW(RP, ph0 + (T) + 3); \
    float2 s0 = bias2, s1 = bias2, s2 = bias2, s3 = bias2; \
    ACCJ(RA, 0); ACCJ(RB, 1); ACCJ(RC, 2); ACCJ(RD, 3); ACCJ(RE, 4); \
    bf162* zr = zbase + ((long)(T) << 7) * 180; \
    bf162 ov; \
    ov.x = __float2bfloat16(RC[2].x + gelu_f(s0.x)); \
    ov.y = __float2bfloat16(RC[2].y + gelu_f(s0.y)); zr[0]   = ov; \
    ov.x = __float2bfloat16(RC[3].x + gelu_f(s1.x)); \
    ov.y = __float2bfloat16(RC[3].y + gelu_f(s1.y)); zr[180] = ov; \
    ov.x = __float2bfloat16(RC[4].x + gelu_f(s2.x)); \
    ov.y = __float2bfloat16(RC[4].y + gelu_f(s2.y)); zr[360] = ov; \
    ov.x = __float2bfloat16(RC[5].x + gelu_f(s3.x)); \
    ov.y = __float2bfloat16(RC[5].y + gelu_f(s3.y)); zr[540] = ov; \
    }

    float2 r0[8], r1[8], r2[8], r3[8], r4[8], r5[8];
    LOADROW(r0, ph0 - 2);
    LOADROW(r1, ph0 - 1);
    LOADROW(r2, ph0);
    LOADROW(r3, ph0 + 1);
    LOADROW(r4, ph0 + 2);

    STEP(0, r0, r1, r2, r3, r4, r5, 1);
    STEP(1, r1, r2, r3, r4, r5, r0, 1);
    STEP(2, r2, r3, r4, r5, r0, r1, 1);
    STEP(3, r3, r4, r5, r0, r1, r2, 1);
    STEP(4, r4, r5, r0, r1, r2, r3, 1);
    STEP(5, r5, r0, r1, r2, r3, r4, 1);
    STEP(6, r0, r1, r2, r3, r4, r5, 1);
    STEP(7, r1, r2, r3, r4, r5, r0, 0);

#undef STEP
#undef ACCJ
#undef LOADROW
}

// ---------------- launch --------------------------------------------------------
extern "C" void kernel_launch(void* const* d_in, const int* in_sizes, int n_in,
                              void* d_out, int out_size, void* d_ws, size_t ws_size,
                              hipStream_t stream) {
    const float* x    = (const float*)d_in[0];
    // d_in[1] = attn_mask: unused (mask recomputed analytically in-kernel)
    const int*   rpi  = (const int*)d_in[2];
    const float* n1w  = (const float*)d_in[3];
    const float* n1b  = (const float*)d_in[4];
    const float* wqkv = (const float*)d_in[5];
    const float* bqkv = (const float*)d_in[6];
    const float* rpb  = (const float*)d_in[7];
    const float* pw   = (const float*)d_in[8];
    const float* pb   = (const float*)d_in[9];
    const float* n2w  = (const float*)d_in[10];
    const float* n2b  = (const float*)d_in[11];
    const float* f1w  = (const float*)d_in[12];
    const float* f1b  = (const float*)d_in[13];
    const float* dww  = (const float*)d_in[14];
    const float* dwb  = (const float*)d_in[15];
    const float* f2w  = (const float*)d_in[16];
    const float* f2b  = (const float*)d_in[17];
    float* out = (float*)d_out;

    // workspace: qkvb 141.6MB | abuf 47.2MB | guard | biasN 1.57MB | WT 0.59MB
    const size_t NEED = 540L * TOK * 2 + 180L * TOK * 2 + 192L * 2
                      + 393216L * 4 + 294912L * 2;
    if (ws_size < NEED) return;

    bf16* qkvb = (bf16*)d_ws;
    bf16* abuf = qkvb + 540L * TOK;
    bf16* ybuf = qkvb;                    // alias: qkv dead after attention
    bf16* zbuf = qkvb + 360L * TOK;       // spans qkvb tail + (abuf-adjacent)
    bf16* guard = qkvb + 720L * TOK;      // 192 zero shorts after abuf
    float* biasN = (float*)(guard + 192);
    bf16* wqkvT = (bf16*)(biasN + 393216);   // [576][192]
    bf16* projT = wqkvT + 110592;            // [192][192]
    bf16* fc1T  = projT + 36864;             // [384][192]
    bf16* fc2T  = fc1T + 73728;              // [192][384]

    wtrans_kernel<180, 540, 192, 576><<<432, 256, 0, stream>>>(wqkv, wqkvT);
    wtrans_kernel<180, 180, 192, 192><<<144, 256, 0, stream>>>(pw, projT);
    wtrans_kernel<180, 360, 192, 384><<<288, 256, 0, stream>>>(f1w, fc1T);
    wtrans_kernel<360, 180, 384, 192><<<288, 256, 0, stream>>>(f2w, fc2T);
    biast_kernel<<<256, 256, 0, stream>>>(rpb, rpi, biasN);
    guardz_kernel<<<1, 192, 0, stream>>>(guard);

    ln_kernel<<<32768, 256, 0, stream>>>(x, n1w, n1b, abuf);
    gemm_xstat<180, 1, 9, 540, 0><<<2048, 256, 0, stream>>>(abuf, wqkvT, bqkv, nullptr, qkvb);
    attn_mfma<<<3072, 256, 0, stream>>>(qkvb, biasN, abuf);         // abuf := attn_out
    gemm_xstat<180, 1, 3, 180, 2><<<2048, 256, 0, stream>>>(abuf, projT, pb, x, out);  // out := x2
    ln_kernel<<<32768, 256, 0, stream>>>(out, n2w, n2b, abuf);      // abuf := xn2
    gemm_xstat<180, 1, 6, 360, 1><<<2048, 256, 0, stream>>>(abuf, fc1T, f1b, nullptr, ybuf);
    dwconv_kernel<<<2880, 256, 0, stream>>>(ybuf, dww, dwb, zbuf);
    gemm_xstat<360, 2, 3, 180, 3><<<2048, 256, 0, stream>>>(zbuf, fc2T, f2b, out, out);
}